// Round 1
// baseline (651.195 us; speedup 1.0000x reference)
//
#include <hip/hip_runtime.h>
#include <math.h>

#define C64 64
#define NCK 4
#define BB  4
#define TT  8
#define HH  96
#define WW  96
#define HW  9216
#define CHW (C64*HW)
#define NTILE 32
#define NBLK_PER_B (HW/NTILE)   /* 288 */

/* workspace layout (float offsets) */
#define OFF_GSUM 0        /* 256  (zeroed) */
#define OFF_S    256      /* 2048 (zeroed) */
#define OFF_COVW 2304     /* 256 */
#define OFF_K    2560     /* 4096 */
#define OFF_MASK 6656     /* 8 */
#define OFF_AC   6664     /* 64 */
#define OFF_BC   6728     /* 64 */
#define OFF_P2   6792     /* 4096 */
#define OFF_B2   10888    /* 64 */
#define OFF_BIAS3 10952   /* 2048 */
#define ZERO_N   2304     /* floats to zero each launch */

__device__ __forceinline__ float gelu_f(float v) {
    return 0.5f * v * (1.0f + erff(v * 0.70710678118654752f));
}

/* ---------------- K1: g_sum[b][c] = sum over (t,h,w) of x5 ---------------- */
__global__ __launch_bounds__(256) void k1_gsum(const float* __restrict__ x,
                                               float* __restrict__ ws) {
    const int blk = blockIdx.x;                 /* (b*T + t)*C + c */
    const float4* p = reinterpret_cast<const float4*>(x + (size_t)blk * HW);
    float s = 0.f;
    for (int i = threadIdx.x; i < HW / 4; i += 256) {
        float4 v = p[i];
        s += v.x + v.y + v.z + v.w;
    }
    #pragma unroll
    for (int off = 32; off; off >>= 1) s += __shfl_down(s, off, 64);
    __shared__ float part[4];
    const int wid = threadIdx.x >> 6, lane = threadIdx.x & 63;
    if (lane == 0) part[wid] = s;
    __syncthreads();
    if (threadIdx.x == 0) {
        float t = part[0] + part[1] + part[2] + part[3];
        int c = blk % C64;
        int b = (blk / C64) / TT;
        atomicAdd(ws + OFF_GSUM + b * C64 + c, t);
    }
}

/* ---------------- K2: all the small/fold math (single block) ---------------- */
__global__ __launch_bounds__(256) void k2_prep(
    const float* __restrict__ tk, const float* __restrict__ kw,
    const float* __restrict__ lsc, const float* __restrict__ tb,
    const float* __restrict__ sc_w1, const float* __restrict__ sc_b1,
    const float* __restrict__ sc_w2, const float* __restrict__ sc_b2,
    const float* __restrict__ diff_gamma, const float* __restrict__ diff_beta,
    const float* __restrict__ diff_mean, const float* __restrict__ diff_var,
    const float* __restrict__ proj_w,
    const float* __restrict__ bn_gamma, const float* __restrict__ bn_beta,
    const float* __restrict__ bn_mean, const float* __restrict__ bn_var,
    const float* __restrict__ temperature,
    float* __restrict__ ws) {
    __shared__ float gsh[BB * C64];
    __shared__ float h1[BB][8];
    __shared__ float wtss[NCK], lss[NCK];
    __shared__ float Msh[64 * 64];
    __shared__ float M2sh[64 * 64];
    __shared__ float v0[64], v1[64];
    __shared__ float lamsh;
    const int tid = threadIdx.x;

    gsh[tid] = ws[OFF_GSUM + tid] * (1.0f / ((float)TT * (float)HW));
    __syncthreads();

    if (tid < BB * 8) {                       /* h1 = gelu(g @ sc_w1^T + b1) */
        int b = tid >> 3, j = tid & 7;
        float a = sc_b1[j];
        for (int c = 0; c < C64; c++) a += gsh[b * C64 + c] * sc_w1[j * C64 + c];
        h1[b][j] = gelu_f(a);
    }
    if (tid == 0) {                            /* wts softmax, ls */
        float mx = -1e30f;
        for (int i = 0; i < NCK; i++) mx = fmaxf(mx, kw[i]);
        float e[NCK], s = 0.f;
        for (int i = 0; i < NCK; i++) { e[i] = expf(kw[i] - mx); s += e[i]; }
        for (int i = 0; i < NCK; i++) { wtss[i] = e[i] / s; lss[i] = expf(lsc[i]); }
    }
    if (tid == 1) {                            /* mask = softmax(mean_c tb) */
        float m[TT], mx = -1e30f;
        for (int t = 0; t < TT; t++) {
            float a = 0.f;
            for (int c = 0; c < C64; c++) a += tb[c * TT + t];
            m[t] = a * (1.0f / (float)C64);
            mx = fmaxf(mx, m[t]);
        }
        float s = 0.f;
        for (int t = 0; t < TT; t++) { m[t] = expf(m[t] - mx); s += m[t]; }
        for (int t = 0; t < TT; t++) ws[OFF_MASK + t] = m[t] / s;
    }
    __syncthreads();

    {   /* cov_w[b][c] = sigmoid(cov[b][C+c]) */
        int b = tid >> 6, c = tid & 63;
        float a = sc_b2[C64 + c];
        for (int j = 0; j < 8; j++) a += h1[b][j] * sc_w2[(C64 + c) * 8 + j];
        ws[OFF_COVW + b * C64 + c] = 1.f / (1.f + expf(-a));
    }
    /* K[c][s][t] */
    for (int q = tid; q < C64 * TT * TT; q += 256) {
        int c = q >> 6, s8 = (q >> 3) & 7, t8 = q & 7;
        float dt = (float)(s8 - t8);
        float dt2 = dt * dt;
        float a = 0.f;
        for (int i = 0; i < NCK; i++)
            a += wtss[i] * tk[i * C64 + c] * expf(-dt2 / (2.f * lss[i] * lss[i]));
        ws[OFF_K + q] = a;
    }
    if (tid < C64) {                           /* diff BN fold */
        float ac = diff_gamma[tid] * rsqrtf(diff_var[tid] + 1e-5f);
        ws[OFF_AC + tid] = ac;
        ws[OFF_BC + tid] = diff_beta[tid] - ac * diff_mean[tid];
    }
    /* M = P^T P */
    for (int q = tid; q < 4096; q += 256) {
        int i = q >> 6, j = q & 63;
        float a = 0.f;
        for (int k = 0; k < 64; k++) a += proj_w[k * 64 + i] * proj_w[k * 64 + j];
        Msh[q] = a;
    }
    __syncthreads();
    /* M2 = M*M (M symmetric) */
    for (int q = tid; q < 4096; q += 256) {
        int i = q >> 6, j = q & 63;
        float a = 0.f;
        for (int k = 0; k < 64; k++) a += Msh[i * 64 + k] * Msh[k * 64 + j];
        M2sh[q] = a;
    }
    if (tid < 64) v0[tid] = 1.f;
    __syncthreads();
    /* power iteration on M2 (symmetric: column read = row read, conflict-free) */
    for (int it = 0; it < 64; ++it) {
        float y = 0.f;
        if (tid < 64) {
            for (int k = 0; k < 64; k++) y += M2sh[k * 64 + tid] * v0[k];
        }
        float yy = y * y;
        #pragma unroll
        for (int off = 32; off; off >>= 1) yy += __shfl_down(yy, off, 64);
        float nrm = __shfl(yy, 0, 64);
        if (tid < 64) v1[tid] = y * rsqrtf(fmaxf(nrm, 1e-30f));
        __syncthreads();
        if (tid < 64) v0[tid] = v1[tid];
        __syncthreads();
    }
    {   /* lambda = v^T M v  (v normalized) */
        float a = 0.f;
        if (tid < 64) {
            for (int k = 0; k < 64; k++) a += Msh[k * 64 + tid] * v0[k];
            a *= v0[tid];
        }
        #pragma unroll
        for (int off = 32; off; off >>= 1) a += __shfl_down(a, off, 64);
        if (tid == 0) lamsh = a;
    }
    __syncthreads();
    const float sigma = sqrtf(fmaxf(lamsh, 1e-30f));
    const float tau = tanhf(temperature[0]);
    if (tid < 64) {
        float gp = bn_gamma[tid] * rsqrtf(bn_var[tid] + 1e-5f);
        ws[OFF_B2 + tid] = tau * (bn_beta[tid] - gp * bn_mean[tid]);
    }
    for (int q = tid; q < 4096; q += 256) {
        int o = q >> 6, c = q & 63;
        float gp = bn_gamma[o] * rsqrtf(bn_var[o] + 1e-5f);
        ws[OFF_P2 + q] = tau * gp * proj_w[o * 64 + c] / sigma;
    }
}

/* -------- shared tile computation: fills dls (=d), alph, bet -------- */
__device__ __forceinline__ void compute_tile(
    const float* __restrict__ x, const float* __restrict__ diff_w,
    const float* __restrict__ unc_w1, const float* __restrict__ unc_b1,
    const float* __restrict__ unc_w2, const float* __restrict__ unc_b2,
    const float* __restrict__ ws, int b, int n0,
    float* dls, float* alph, float* bet) {
    const int tid = threadIdx.x;
    const int nloc = tid & 31;
    const int n = n0 + nloc;
    float mk[TT];
    #pragma unroll
    for (int t = 0; t < TT; t++) mk[t] = ws[OFF_MASK + t];

    /* phase 1: per (c,n): gp, fused0, diff conv + BN + gelu -> d into LDS */
    #pragma unroll
    for (int p = 0; p < 8; p++) {
        const int c = (tid >> 5) + (p << 3);
        float xr[TT];
        #pragma unroll
        for (int t = 0; t < TT; t++)
            xr[t] = x[(size_t)((b * TT + t) * C64 + c) * HW + n];
        const float cw = ws[OFF_COVW + b * C64 + c];
        const float* kr = ws + OFF_K + c * (TT * TT);
        float f0[TT];
        #pragma unroll
        for (int s = 0; s < TT; s++) {
            float a = 0.f;
            #pragma unroll
            for (int t = 0; t < TT; t++) a += kr[s * TT + t] * xr[t];
            f0[s] = a * cw + xr[s] * mk[s] * (1.f - cw);
        }
        const float w0 = diff_w[c * 3 + 0], w1 = diff_w[c * 3 + 1], w2 = diff_w[c * 3 + 2];
        const float ac = ws[OFF_AC + c], bc = ws[OFF_BC + c];
        #pragma unroll
        for (int t = 0; t < TT; t++) {
            float pre = w1 * f0[t];
            if (t > 0)      pre += w0 * f0[t - 1];
            if (t < TT - 1) pre += w2 * f0[t + 1];
            dls[(c * TT + t) * NTILE + nloc] = gelu_f(ac * pre + bc);
        }
    }
    __syncthreads();

    /* phase 2: per (t,n): uncertainty MLP -> alpha, beta */
    {
        const int t = tid >> 5;
        float dcol[C64];
        #pragma unroll
        for (int c = 0; c < C64; c++) dcol[c] = dls[(c * TT + t) * NTILE + nloc];
        float u1[16];
        #pragma unroll
        for (int o = 0; o < 16; o++) {
            float a = unc_b1[o];
            const float* wr = unc_w1 + o * C64;
            #pragma unroll
            for (int c = 0; c < C64; c++) a += wr[c] * dcol[c];
            u1[o] = gelu_f(a);
        }
        float mu = unc_b2[0], va = unc_b2[1];
        #pragma unroll
        for (int o = 0; o < 16; o++) {
            mu += unc_w2[o] * u1[o];
            va += unc_w2[16 + o] * u1[o];
        }
        const float vp = va + 1e-6f;          /* fused = alpha*d + beta (stable form) */
        const float inv = 1.f / (1.f + vp);
        alph[tid] = vp * inv;
        bet[tid] = mu * inv;
    }
    __syncthreads();
}

/* ---------------- K3: S[b][c][t] = sum_n fused ---------------- */
__global__ __launch_bounds__(256) void k3_main(
    const float* __restrict__ x, const float* __restrict__ diff_w,
    const float* __restrict__ unc_w1, const float* __restrict__ unc_b1,
    const float* __restrict__ unc_w2, const float* __restrict__ unc_b2,
    float* __restrict__ ws) {
    __shared__ float dls[C64 * TT * NTILE];
    __shared__ float alph[256], bet[256];
    const int tile = blockIdx.x;
    const int b = tile / NBLK_PER_B;
    const int n0 = (tile % NBLK_PER_B) * NTILE;
    compute_tile(x, diff_w, unc_w1, unc_b1, unc_w2, unc_b2, ws, b, n0, dls, alph, bet);
    const int tid = threadIdx.x, nloc = tid & 31;
    #pragma unroll
    for (int p = 0; p < 8; p++) {
        const int c = (tid >> 5) + (p << 3);
        #pragma unroll
        for (int t = 0; t < TT; t++) {
            float v = alph[t * 32 + nloc] * dls[(c * TT + t) * NTILE + nloc] + bet[t * 32 + nloc];
            #pragma unroll
            for (int off = 16; off; off >>= 1) v += __shfl_xor(v, off, 32);
            if (nloc == 0) atomicAdd(ws + OFF_S + (b * C64 + c) * TT + t, v);
        }
    }
}

/* ---------------- K4: bias3[b][o][t] = B2[o] + sum_c P2[o][c]*pm[b][c][t] ---------------- */
__global__ __launch_bounds__(64) void k4_bias(
    const float* __restrict__ pool_w, const float* __restrict__ pool_b,
    float* __restrict__ ws) {
    const int b = blockIdx.x >> 3, t = blockIdx.x & 7;
    const int o = threadIdx.x;
    __shared__ float pm[C64];
    float a = 0.f;
    for (int k = 0; k < 3; k++) {
        int tt = t + k - 1;
        if (tt < 0 || tt >= TT) continue;
        const float* Sp = ws + OFF_S + b * C64 * TT + tt;
        for (int cp = 0; cp < C64; cp++)
            a += pool_w[(o * C64 + cp) * 3 + k] * Sp[cp * TT];
    }
    pm[o] = pool_b[o] + a * (1.0f / (float)HW);
    __syncthreads();
    float bb = ws[OFF_B2 + o];
    const float* pr = ws + OFF_P2 + o * C64;
    for (int c = 0; c < C64; c++) bb += pr[c] * pm[c];
    ws[OFF_BIAS3 + (b * C64 + o) * TT + t] = bb;
}

/* ---------------- K5: recompute tile, project, residual, write out ---------------- */
__global__ __launch_bounds__(256) void k5_final(
    const float* __restrict__ x, const float* __restrict__ diff_w,
    const float* __restrict__ unc_w1, const float* __restrict__ unc_b1,
    const float* __restrict__ unc_w2, const float* __restrict__ unc_b2,
    const float* __restrict__ ws, float* __restrict__ out) {
    __shared__ float dls[C64 * TT * NTILE];
    __shared__ float alph[256], bet[256];
    const int tile = blockIdx.x;
    const int b = tile / NBLK_PER_B;
    const int n0 = (tile % NBLK_PER_B) * NTILE;
    compute_tile(x, diff_w, unc_w1, unc_b1, unc_w2, unc_b2, ws, b, n0, dls, alph, bet);
    const int tid = threadIdx.x, nloc = tid & 31;
    /* fused in place */
    #pragma unroll
    for (int p = 0; p < 8; p++) {
        const int c = (tid >> 5) + (p << 3);
        #pragma unroll
        for (int t = 0; t < TT; t++) {
            const int idx = (c * TT + t) * NTILE + nloc;
            dls[idx] = alph[t * 32 + nloc] * dls[idx] + bet[t * 32 + nloc];
        }
    }
    __syncthreads();
    /* projection + residual */
    {
        const int t = tid >> 5;
        float fcol[C64];
        #pragma unroll
        for (int c = 0; c < C64; c++) fcol[c] = dls[(c * TT + t) * NTILE + nloc];
        const size_t xb = (size_t)(b * TT + t) * CHW + n0 + nloc;
        for (int o = 0; o < C64; o++) {
            float a = ws[OFF_BIAS3 + (b * C64 + o) * TT + t];
            const float* pr = ws + OFF_P2 + o * C64;
            #pragma unroll
            for (int c = 0; c < C64; c++) a += pr[c] * fcol[c];
            out[xb + (size_t)o * HW] = x[xb + (size_t)o * HW] + a;
        }
    }
}

extern "C" void kernel_launch(void* const* d_in, const int* in_sizes, int n_in,
                              void* d_out, int out_size, void* d_ws, size_t ws_size,
                              hipStream_t stream) {
    const float* x           = (const float*)d_in[0];
    /* d_in[1] = t (int scalar), known at compile time */
    const float* tk          = (const float*)d_in[2];
    const float* kw          = (const float*)d_in[3];
    const float* lsc         = (const float*)d_in[4];
    const float* tb          = (const float*)d_in[5];
    const float* sc_w1       = (const float*)d_in[6];
    const float* sc_b1       = (const float*)d_in[7];
    const float* sc_w2       = (const float*)d_in[8];
    const float* sc_b2       = (const float*)d_in[9];
    const float* diff_w      = (const float*)d_in[10];
    const float* diff_gamma  = (const float*)d_in[11];
    const float* diff_beta   = (const float*)d_in[12];
    const float* diff_mean   = (const float*)d_in[13];
    const float* diff_var    = (const float*)d_in[14];
    const float* unc_w1      = (const float*)d_in[15];
    const float* unc_b1      = (const float*)d_in[16];
    const float* unc_w2      = (const float*)d_in[17];
    const float* unc_b2      = (const float*)d_in[18];
    const float* pool_w      = (const float*)d_in[19];
    const float* pool_b      = (const float*)d_in[20];
    const float* proj_w      = (const float*)d_in[21];
    const float* bn_gamma    = (const float*)d_in[22];
    const float* bn_beta     = (const float*)d_in[23];
    const float* bn_mean     = (const float*)d_in[24];
    const float* bn_var      = (const float*)d_in[25];
    const float* temperature = (const float*)d_in[26];
    float* ws = (float*)d_ws;
    float* out = (float*)d_out;

    hipMemsetAsync(ws, 0, ZERO_N * sizeof(float), stream);
    k1_gsum<<<dim3(BB * TT * C64), dim3(256), 0, stream>>>(x, ws);
    k2_prep<<<dim3(1), dim3(256), 0, stream>>>(tk, kw, lsc, tb, sc_w1, sc_b1,
                                               sc_w2, sc_b2, diff_gamma, diff_beta,
                                               diff_mean, diff_var, proj_w, bn_gamma,
                                               bn_beta, bn_mean, bn_var, temperature, ws);
    k3_main<<<dim3(BB * NBLK_PER_B), dim3(256), 0, stream>>>(x, diff_w, unc_w1, unc_b1,
                                                             unc_w2, unc_b2, ws);
    k4_bias<<<dim3(BB * TT), dim3(64), 0, stream>>>(pool_w, pool_b, ws);
    k5_final<<<dim3(BB * NBLK_PER_B), dim3(256), 0, stream>>>(x, diff_w, unc_w1, unc_b1,
                                                              unc_w2, unc_b2, ws, out);
}

// Round 2
// 601.735 us; speedup vs baseline: 1.0822x; 1.0822x over previous
//
#include <hip/hip_runtime.h>
#include <math.h>

#define C64 64
#define NCK 4
#define BB  4
#define TT  8
#define HH  96
#define WW  96
#define HW  9216
#define CHW (C64*HW)
#define NTILE 32
#define NBLK_PER_B (HW/NTILE)   /* 288 */

/* workspace layout (float offsets) */
#define OFF_GSUM 0        /* 256  (zeroed) */
#define OFF_S    256      /* 2048 (zeroed) */
#define OFF_COVW 2304     /* 256 */
#define OFF_K    2560     /* 4096 */
#define OFF_MASK 6656     /* 8 */
#define OFF_AC   6664     /* 64 */
#define OFF_BC   6728     /* 64 */
#define OFF_P2   6792     /* 4096 */
#define OFF_B2   10888    /* 64 */
#define OFF_BIAS3 10952   /* 2048 */
#define ZERO_N   2304     /* floats to zero each launch */

__device__ __forceinline__ float gelu_f(float v) {
    return 0.5f * v * (1.0f + erff(v * 0.70710678118654752f));
}
__device__ __forceinline__ unsigned short f2bf(float f) {
    union { float f; unsigned int u; } v; v.f = f;
    unsigned int r = (v.u + 0x7fffu + ((v.u >> 16) & 1u)) >> 16;
    return (unsigned short)r;
}
__device__ __forceinline__ float bf2f(unsigned short h) {
    union { unsigned int u; float f; } v; v.u = ((unsigned int)h) << 16;
    return v.f;
}

/* ---------------- K1: g_sum[b][c] = sum over (t,h,w) of x5 ---------------- */
__global__ __launch_bounds__(256) void k1_gsum(const float* __restrict__ x,
                                               float* __restrict__ ws) {
    const int blk = blockIdx.x;                 /* (b*T + t)*C + c */
    const float4* p = reinterpret_cast<const float4*>(x + (size_t)blk * HW);
    float s = 0.f;
    for (int i = threadIdx.x; i < HW / 4; i += 256) {
        float4 v = p[i];
        s += v.x + v.y + v.z + v.w;
    }
    #pragma unroll
    for (int off = 32; off; off >>= 1) s += __shfl_down(s, off, 64);
    __shared__ float part[4];
    const int wid = threadIdx.x >> 6, lane = threadIdx.x & 63;
    if (lane == 0) part[wid] = s;
    __syncthreads();
    if (threadIdx.x == 0) {
        float t = part[0] + part[1] + part[2] + part[3];
        int c = blk % C64;
        int b = (blk / C64) / TT;
        atomicAdd(ws + OFF_GSUM + b * C64 + c, t);
    }
}

/* ---------------- K2: all the small/fold math (single block) ---------------- */
__global__ __launch_bounds__(256) void k2_prep(
    const float* __restrict__ tk, const float* __restrict__ kw,
    const float* __restrict__ lsc, const float* __restrict__ tb,
    const float* __restrict__ sc_w1, const float* __restrict__ sc_b1,
    const float* __restrict__ sc_w2, const float* __restrict__ sc_b2,
    const float* __restrict__ diff_gamma, const float* __restrict__ diff_beta,
    const float* __restrict__ diff_mean, const float* __restrict__ diff_var,
    const float* __restrict__ proj_w,
    const float* __restrict__ bn_gamma, const float* __restrict__ bn_beta,
    const float* __restrict__ bn_mean, const float* __restrict__ bn_var,
    const float* __restrict__ temperature,
    float* __restrict__ ws) {
    __shared__ float gsh[BB * C64];
    __shared__ float h1[BB][8];
    __shared__ float wtss[NCK], lss[NCK];
    __shared__ float Msh[64 * 64];
    __shared__ float M2sh[64 * 64];
    __shared__ float v0[64], v1[64];
    __shared__ float lamsh;
    const int tid = threadIdx.x;

    gsh[tid] = ws[OFF_GSUM + tid] * (1.0f / ((float)TT * (float)HW));
    __syncthreads();

    if (tid < BB * 8) {                       /* h1 = gelu(g @ sc_w1^T + b1) */
        int b = tid >> 3, j = tid & 7;
        float a = sc_b1[j];
        for (int c = 0; c < C64; c++) a += gsh[b * C64 + c] * sc_w1[j * C64 + c];
        h1[b][j] = gelu_f(a);
    }
    if (tid == 0) {                            /* wts softmax, ls */
        float mx = -1e30f;
        for (int i = 0; i < NCK; i++) mx = fmaxf(mx, kw[i]);
        float e[NCK], s = 0.f;
        for (int i = 0; i < NCK; i++) { e[i] = expf(kw[i] - mx); s += e[i]; }
        for (int i = 0; i < NCK; i++) { wtss[i] = e[i] / s; lss[i] = expf(lsc[i]); }
    }
    if (tid == 1) {                            /* mask = softmax(mean_c tb) */
        float m[TT], mx = -1e30f;
        for (int t = 0; t < TT; t++) {
            float a = 0.f;
            for (int c = 0; c < C64; c++) a += tb[c * TT + t];
            m[t] = a * (1.0f / (float)C64);
            mx = fmaxf(mx, m[t]);
        }
        float s = 0.f;
        for (int t = 0; t < TT; t++) { m[t] = expf(m[t] - mx); s += m[t]; }
        for (int t = 0; t < TT; t++) ws[OFF_MASK + t] = m[t] / s;
    }
    __syncthreads();

    {   /* cov_w[b][c] = sigmoid(cov[b][C+c]) */
        int b = tid >> 6, c = tid & 63;
        float a = sc_b2[C64 + c];
        for (int j = 0; j < 8; j++) a += h1[b][j] * sc_w2[(C64 + c) * 8 + j];
        ws[OFF_COVW + b * C64 + c] = 1.f / (1.f + expf(-a));
    }
    /* K[c][s][t] */
    for (int q = tid; q < C64 * TT * TT; q += 256) {
        int c = q >> 6, s8 = (q >> 3) & 7, t8 = q & 7;
        float dt = (float)(s8 - t8);
        float dt2 = dt * dt;
        float a = 0.f;
        for (int i = 0; i < NCK; i++)
            a += wtss[i] * tk[i * C64 + c] * expf(-dt2 / (2.f * lss[i] * lss[i]));
        ws[OFF_K + q] = a;
    }
    if (tid < C64) {                           /* diff BN fold */
        float ac = diff_gamma[tid] * rsqrtf(diff_var[tid] + 1e-5f);
        ws[OFF_AC + tid] = ac;
        ws[OFF_BC + tid] = diff_beta[tid] - ac * diff_mean[tid];
    }
    /* M = P^T P */
    for (int q = tid; q < 4096; q += 256) {
        int i = q >> 6, j = q & 63;
        float a = 0.f;
        for (int k = 0; k < 64; k++) a += proj_w[k * 64 + i] * proj_w[k * 64 + j];
        Msh[q] = a;
    }
    __syncthreads();
    /* M2 = M*M (M symmetric) */
    for (int q = tid; q < 4096; q += 256) {
        int i = q >> 6, j = q & 63;
        float a = 0.f;
        for (int k = 0; k < 64; k++) a += Msh[i * 64 + k] * Msh[k * 64 + j];
        M2sh[q] = a;
    }
    if (tid < 64) v0[tid] = 1.f;
    __syncthreads();
    /* power iteration on M2 (symmetric: column read = row read, conflict-free) */
    for (int it = 0; it < 40; ++it) {
        float y = 0.f;
        if (tid < 64) {
            for (int k = 0; k < 64; k++) y += M2sh[k * 64 + tid] * v0[k];
        }
        float yy = y * y;
        #pragma unroll
        for (int off = 32; off; off >>= 1) yy += __shfl_down(yy, off, 64);
        float nrm = __shfl(yy, 0, 64);
        if (tid < 64) v1[tid] = y * rsqrtf(fmaxf(nrm, 1e-30f));
        __syncthreads();
        if (tid < 64) v0[tid] = v1[tid];
        __syncthreads();
    }
    {   /* lambda = v^T M v  (v normalized) */
        float a = 0.f;
        if (tid < 64) {
            for (int k = 0; k < 64; k++) a += Msh[k * 64 + tid] * v0[k];
            a *= v0[tid];
        }
        #pragma unroll
        for (int off = 32; off; off >>= 1) a += __shfl_down(a, off, 64);
        if (tid == 0) lamsh = a;
    }
    __syncthreads();
    const float sigma = sqrtf(fmaxf(lamsh, 1e-30f));
    const float tau = tanhf(temperature[0]);
    if (tid < 64) {
        float gp = bn_gamma[tid] * rsqrtf(bn_var[tid] + 1e-5f);
        ws[OFF_B2 + tid] = tau * (bn_beta[tid] - gp * bn_mean[tid]);
    }
    for (int q = tid; q < 4096; q += 256) {
        int o = q >> 6, c = q & 63;
        float gp = bn_gamma[o] * rsqrtf(bn_var[o] + 1e-5f);
        ws[OFF_P2 + q] = tau * gp * proj_w[o * 64 + c] / sigma;
    }
}

/* -------- shared tile computation: fills dls (=d, bf16), alph, bet -------- */
__device__ __forceinline__ void compute_tile(
    const float* __restrict__ x, const float* __restrict__ diff_w,
    const float* __restrict__ unc_w1, const float* __restrict__ unc_b1,
    const float* __restrict__ unc_w2, const float* __restrict__ unc_b2,
    const float* __restrict__ ws, int b, int n0,
    unsigned short* dls, float* alph, float* bet) {
    const int tid = threadIdx.x;
    const int nloc = tid & 31;
    const int n = n0 + nloc;
    float mk[TT];
    #pragma unroll
    for (int t = 0; t < TT; t++) mk[t] = ws[OFF_MASK + t];

    /* phase 1: per (c,n): gp, fused0, diff conv + BN + gelu -> d into LDS (bf16) */
    #pragma unroll
    for (int p = 0; p < 8; p++) {
        const int c = (tid >> 5) + (p << 3);
        float xr[TT];
        #pragma unroll
        for (int t = 0; t < TT; t++)
            xr[t] = x[(size_t)((b * TT + t) * C64 + c) * HW + n];
        const float cw = ws[OFF_COVW + b * C64 + c];
        const float* kr = ws + OFF_K + c * (TT * TT);
        float f0[TT];
        #pragma unroll
        for (int s = 0; s < TT; s++) {
            float a = 0.f;
            #pragma unroll
            for (int t = 0; t < TT; t++) a += kr[s * TT + t] * xr[t];
            f0[s] = a * cw + xr[s] * mk[s] * (1.f - cw);
        }
        const float w0 = diff_w[c * 3 + 0], w1 = diff_w[c * 3 + 1], w2 = diff_w[c * 3 + 2];
        const float ac = ws[OFF_AC + c], bc = ws[OFF_BC + c];
        #pragma unroll
        for (int t = 0; t < TT; t++) {
            float pre = w1 * f0[t];
            if (t > 0)      pre += w0 * f0[t - 1];
            if (t < TT - 1) pre += w2 * f0[t + 1];
            dls[(c * TT + t) * NTILE + nloc] = f2bf(gelu_f(ac * pre + bc));
        }
    }
    __syncthreads();

    /* phase 2: per (t,n): uncertainty MLP -> alpha, beta */
    {
        const int t = tid >> 5;
        float dcol[C64];
        #pragma unroll
        for (int c = 0; c < C64; c++) dcol[c] = bf2f(dls[(c * TT + t) * NTILE + nloc]);
        float u1[16];
        #pragma unroll
        for (int o = 0; o < 16; o++) {
            float a = unc_b1[o];
            const float* wr = unc_w1 + o * C64;
            #pragma unroll
            for (int c = 0; c < C64; c++) a += wr[c] * dcol[c];
            u1[o] = gelu_f(a);
        }
        float mu = unc_b2[0], va = unc_b2[1];
        #pragma unroll
        for (int o = 0; o < 16; o++) {
            mu += unc_w2[o] * u1[o];
            va += unc_w2[16 + o] * u1[o];
        }
        const float vp = va + 1e-6f;          /* fused = alpha*d + beta (stable form) */
        const float inv = 1.f / (1.f + vp);
        alph[tid] = vp * inv;
        bet[tid] = mu * inv;
    }
    __syncthreads();
}

/* ------- K3: tile once: fused, S sums, projection, out = x + P2*fused ------- */
__global__ __launch_bounds__(256) void k3_main(
    const float* __restrict__ x, const float* __restrict__ diff_w,
    const float* __restrict__ unc_w1, const float* __restrict__ unc_b1,
    const float* __restrict__ unc_w2, const float* __restrict__ unc_b2,
    float* __restrict__ ws, float* __restrict__ out) {
    __shared__ unsigned short dls[C64 * TT * NTILE];
    __shared__ float alph[256], bet[256];
    const int tile = blockIdx.x;
    const int b = tile / NBLK_PER_B;
    const int n0 = (tile % NBLK_PER_B) * NTILE;
    compute_tile(x, diff_w, unc_w1, unc_b1, unc_w2, unc_b2, ws, b, n0, dls, alph, bet);
    const int tid = threadIdx.x, nloc = tid & 31;

    /* fused in place (bf16) + S partial sums */
    #pragma unroll
    for (int p = 0; p < 8; p++) {
        const int c = (tid >> 5) + (p << 3);
        #pragma unroll
        for (int t = 0; t < TT; t++) {
            const int idx = (c * TT + t) * NTILE + nloc;
            float f = alph[t * 32 + nloc] * bf2f(dls[idx]) + bet[t * 32 + nloc];
            dls[idx] = f2bf(f);
            float v = f;
            #pragma unroll
            for (int off = 16; off; off >>= 1) v += __shfl_xor(v, off, 32);
            if (nloc == 0) atomicAdd(ws + OFF_S + (b * C64 + c) * TT + t, v);
        }
    }
    __syncthreads();

    /* projection + residual (bias3 added later by k5_bias) */
    {
        const int t = tid >> 5;
        float fcol[C64];
        #pragma unroll
        for (int c = 0; c < C64; c++) fcol[c] = bf2f(dls[(c * TT + t) * NTILE + nloc]);
        const size_t xb = (size_t)(b * TT + t) * CHW + n0 + nloc;
        for (int o = 0; o < C64; o++) {
            const float4* pr4 = reinterpret_cast<const float4*>(ws + OFF_P2 + o * C64);
            float a = 0.f;
            #pragma unroll
            for (int c4 = 0; c4 < 16; c4++) {
                float4 w4 = pr4[c4];
                a += w4.x * fcol[c4 * 4 + 0];
                a += w4.y * fcol[c4 * 4 + 1];
                a += w4.z * fcol[c4 * 4 + 2];
                a += w4.w * fcol[c4 * 4 + 3];
            }
            out[xb + (size_t)o * HW] = x[xb + (size_t)o * HW] + a;
        }
    }
}

/* ---------------- K4: bias3[b][o][t] = B2[o] + sum_c P2[o][c]*pm[b][c][t] ---------------- */
__global__ __launch_bounds__(64) void k4_bias(
    const float* __restrict__ pool_w, const float* __restrict__ pool_b,
    float* __restrict__ ws) {
    const int b = blockIdx.x >> 3, t = blockIdx.x & 7;
    const int o = threadIdx.x;
    __shared__ float pm[C64];
    float a = 0.f;
    for (int k = 0; k < 3; k++) {
        int tt = t + k - 1;
        if (tt < 0 || tt >= TT) continue;
        const float* Sp = ws + OFF_S + b * C64 * TT + tt;
        for (int cp = 0; cp < C64; cp++)
            a += pool_w[(o * C64 + cp) * 3 + k] * Sp[cp * TT];
    }
    pm[o] = pool_b[o] + a * (1.0f / (float)HW);
    __syncthreads();
    float bb = ws[OFF_B2 + o];
    const float* pr = ws + OFF_P2 + o * C64;
    for (int c = 0; c < C64; c++) bb += pr[c] * pm[c];
    ws[OFF_BIAS3 + (b * C64 + o) * TT + t] = bb;
}

/* ---------------- K5: out[bt,o,:] += bias3[b][o][t]  (broadcast RMW) ---------------- */
__global__ __launch_bounds__(256) void k5_bias(
    const float* __restrict__ ws, float* __restrict__ out) {
    const int plane = blockIdx.x;               /* bt*64 + o */
    const int o = plane & 63;
    const int bt = plane >> 6;
    const int b = bt >> 3, t = bt & 7;
    const float bias = ws[OFF_BIAS3 + (b * C64 + o) * TT + t];
    float4* p = reinterpret_cast<float4*>(out + (size_t)plane * HW);
    #pragma unroll
    for (int i = 0; i < 9; i++) {
        const int idx = threadIdx.x + i * 256;
        float4 v = p[idx];
        v.x += bias; v.y += bias; v.z += bias; v.w += bias;
        p[idx] = v;
    }
}

extern "C" void kernel_launch(void* const* d_in, const int* in_sizes, int n_in,
                              void* d_out, int out_size, void* d_ws, size_t ws_size,
                              hipStream_t stream) {
    const float* x           = (const float*)d_in[0];
    const float* tk          = (const float*)d_in[2];
    const float* kw          = (const float*)d_in[3];
    const float* lsc         = (const float*)d_in[4];
    const float* tb          = (const float*)d_in[5];
    const float* sc_w1       = (const float*)d_in[6];
    const float* sc_b1       = (const float*)d_in[7];
    const float* sc_w2       = (const float*)d_in[8];
    const float* sc_b2       = (const float*)d_in[9];
    const float* diff_w      = (const float*)d_in[10];
    const float* diff_gamma  = (const float*)d_in[11];
    const float* diff_beta   = (const float*)d_in[12];
    const float* diff_mean   = (const float*)d_in[13];
    const float* diff_var    = (const float*)d_in[14];
    const float* unc_w1      = (const float*)d_in[15];
    const float* unc_b1      = (const float*)d_in[16];
    const float* unc_w2      = (const float*)d_in[17];
    const float* unc_b2      = (const float*)d_in[18];
    const float* pool_w      = (const float*)d_in[19];
    const float* pool_b      = (const float*)d_in[20];
    const float* proj_w      = (const float*)d_in[21];
    const float* bn_gamma    = (const float*)d_in[22];
    const float* bn_beta     = (const float*)d_in[23];
    const float* bn_mean     = (const float*)d_in[24];
    const float* bn_var      = (const float*)d_in[25];
    const float* temperature = (const float*)d_in[26];
    float* ws = (float*)d_ws;
    float* out = (float*)d_out;

    hipMemsetAsync(ws, 0, ZERO_N * sizeof(float), stream);
    k1_gsum<<<dim3(BB * TT * C64), dim3(256), 0, stream>>>(x, ws);
    k2_prep<<<dim3(1), dim3(256), 0, stream>>>(tk, kw, lsc, tb, sc_w1, sc_b1,
                                               sc_w2, sc_b2, diff_gamma, diff_beta,
                                               diff_mean, diff_var, proj_w, bn_gamma,
                                               bn_beta, bn_mean, bn_var, temperature, ws);
    k3_main<<<dim3(BB * NBLK_PER_B), dim3(256), 0, stream>>>(x, diff_w, unc_w1, unc_b1,
                                                             unc_w2, unc_b2, ws, out);
    k4_bias<<<dim3(BB * TT), dim3(64), 0, stream>>>(pool_w, pool_b, ws);
    k5_bias<<<dim3(BB * TT * C64), dim3(256), 0, stream>>>(ws, out);
}

// Round 4
// 507.849 us; speedup vs baseline: 1.2823x; 1.1849x over previous
//
#include <hip/hip_runtime.h>
#include <math.h>

#define C64 64
#define NCK 4
#define BB  4
#define TT  8
#define HH  96
#define WW  96
#define HW  9216
#define CHW (C64*HW)
#define NTILE 32
#define NBLK_PER_B (HW/NTILE)   /* 288 */

/* workspace layout (float offsets) */
#define OFF_GSUM 0        /* 256  (zeroed) */
#define OFF_S    256      /* 2048 (zeroed) */
#define OFF_COVW 2304     /* 256 */
#define OFF_K    2560     /* 4096 */
#define OFF_MASK 6656     /* 8 */
#define OFF_AC   6664     /* 64 */
#define OFF_BC   6728     /* 64 */
#define OFF_P2   6792     /* 4096 (f32, for k4) */
#define OFF_B2   10888    /* 64 */
#define OFF_BIAS3 10952   /* 2048 */
#define OFF_P2BF 13000    /* 4096 ushorts = 2048 float slots (bf16 P2) */
#define ZERO_N   2304     /* floats to zero each launch */

typedef __attribute__((ext_vector_type(8))) short short8;
typedef __attribute__((ext_vector_type(4))) float f32x4;

__device__ __forceinline__ float gelu_f(float v) {
    return 0.5f * v * (1.0f + erff(v * 0.70710678118654752f));
}
__device__ __forceinline__ unsigned short f2bf(float f) {
    union { float f; unsigned int u; } v; v.f = f;
    unsigned int r = (v.u + 0x7fffu + ((v.u >> 16) & 1u)) >> 16;
    return (unsigned short)r;
}
__device__ __forceinline__ float bf2f(unsigned short h) {
    union { unsigned int u; float f; } v; v.u = ((unsigned int)h) << 16;
    return v.f;
}
/* swizzled LDS index (ushort units): row tn in [0,256), col c in [0,64) */
__device__ __forceinline__ int swz(int tn, int c) {
    return (tn << 6) + (c ^ ((tn & 7) << 3));
}

/* ---------------- K1: g_sum[b][c] = sum over (t,h,w) of x5 ---------------- */
__global__ __launch_bounds__(256) void k1_gsum(const float* __restrict__ x,
                                               float* __restrict__ ws) {
    const int blk = blockIdx.x;                 /* (b*T + t)*C + c */
    const float4* p = reinterpret_cast<const float4*>(x + (size_t)blk * HW);
    float s = 0.f;
    for (int i = threadIdx.x; i < HW / 4; i += 256) {
        float4 v = p[i];
        s += v.x + v.y + v.z + v.w;
    }
    #pragma unroll
    for (int off = 32; off; off >>= 1) s += __shfl_down(s, off, 64);
    __shared__ float part[4];
    const int wid = threadIdx.x >> 6, lane = threadIdx.x & 63;
    if (lane == 0) part[wid] = s;
    __syncthreads();
    if (threadIdx.x == 0) {
        float t = part[0] + part[1] + part[2] + part[3];
        int c = blk % C64;
        int b = (blk / C64) / TT;
        atomicAdd(ws + OFF_GSUM + b * C64 + c, t);
    }
}

/* ---------------- K2: all the small/fold math (single block) ---------------- */
__global__ __launch_bounds__(256) void k2_prep(
    const float* __restrict__ tk, const float* __restrict__ kw,
    const float* __restrict__ lsc, const float* __restrict__ tb,
    const float* __restrict__ sc_w1, const float* __restrict__ sc_b1,
    const float* __restrict__ sc_w2, const float* __restrict__ sc_b2,
    const float* __restrict__ diff_gamma, const float* __restrict__ diff_beta,
    const float* __restrict__ diff_mean, const float* __restrict__ diff_var,
    const float* __restrict__ proj_w,
    const float* __restrict__ bn_gamma, const float* __restrict__ bn_beta,
    const float* __restrict__ bn_mean, const float* __restrict__ bn_var,
    const float* __restrict__ temperature,
    float* __restrict__ ws) {
    __shared__ float gsh[BB * C64];
    __shared__ float h1[BB][8];
    __shared__ float wtss[NCK], lss[NCK];
    __shared__ float Msh[64 * 64];
    __shared__ float M2sh[64 * 64];
    __shared__ float v0[64], v1[64];
    __shared__ float lamsh;
    const int tid = threadIdx.x;

    gsh[tid] = ws[OFF_GSUM + tid] * (1.0f / ((float)TT * (float)HW));
    __syncthreads();

    if (tid < BB * 8) {                       /* h1 = gelu(g @ sc_w1^T + b1) */
        int b = tid >> 3, j = tid & 7;
        float a = sc_b1[j];
        for (int c = 0; c < C64; c++) a += gsh[b * C64 + c] * sc_w1[j * C64 + c];
        h1[b][j] = gelu_f(a);
    }
    if (tid == 0) {                            /* wts softmax, ls */
        float mx = -1e30f;
        for (int i = 0; i < NCK; i++) mx = fmaxf(mx, kw[i]);
        float e[NCK], s = 0.f;
        for (int i = 0; i < NCK; i++) { e[i] = expf(kw[i] - mx); s += e[i]; }
        for (int i = 0; i < NCK; i++) { wtss[i] = e[i] / s; lss[i] = expf(lsc[i]); }
    }
    if (tid == 1) {                            /* mask = softmax(mean_c tb) */
        float m[TT], mx = -1e30f;
        for (int t = 0; t < TT; t++) {
            float a = 0.f;
            for (int c = 0; c < C64; c++) a += tb[c * TT + t];
            m[t] = a * (1.0f / (float)C64);
            mx = fmaxf(mx, m[t]);
        }
        float s = 0.f;
        for (int t = 0; t < TT; t++) { m[t] = expf(m[t] - mx); s += m[t]; }
        for (int t = 0; t < TT; t++) ws[OFF_MASK + t] = m[t] / s;
    }
    __syncthreads();

    {   /* cov_w[b][c] = sigmoid(cov[b][C+c]) */
        int b = tid >> 6, c = tid & 63;
        float a = sc_b2[C64 + c];
        for (int j = 0; j < 8; j++) a += h1[b][j] * sc_w2[(C64 + c) * 8 + j];
        ws[OFF_COVW + b * C64 + c] = 1.f / (1.f + expf(-a));
    }
    /* K[c][s][t] */
    for (int q = tid; q < C64 * TT * TT; q += 256) {
        int c = q >> 6, s8 = (q >> 3) & 7, t8 = q & 7;
        float dt = (float)(s8 - t8);
        float dt2 = dt * dt;
        float a = 0.f;
        for (int i = 0; i < NCK; i++)
            a += wtss[i] * tk[i * C64 + c] * expf(-dt2 / (2.f * lss[i] * lss[i]));
        ws[OFF_K + q] = a;
    }
    if (tid < C64) {                           /* diff BN fold */
        float ac = diff_gamma[tid] * rsqrtf(diff_var[tid] + 1e-5f);
        ws[OFF_AC + tid] = ac;
        ws[OFF_BC + tid] = diff_beta[tid] - ac * diff_mean[tid];
    }
    /* M = P^T P */
    for (int q = tid; q < 4096; q += 256) {
        int i = q >> 6, j = q & 63;
        float a = 0.f;
        for (int k = 0; k < 64; k++) a += proj_w[k * 64 + i] * proj_w[k * 64 + j];
        Msh[q] = a;
    }
    __syncthreads();
    /* M2 = M*M (M symmetric) */
    for (int q = tid; q < 4096; q += 256) {
        int i = q >> 6, j = q & 63;
        float a = 0.f;
        for (int k = 0; k < 64; k++) a += Msh[i * 64 + k] * Msh[k * 64 + j];
        M2sh[q] = a;
    }
    if (tid < 64) v0[tid] = 1.f;
    __syncthreads();
    /* power iteration on M2 */
    for (int it = 0; it < 24; ++it) {
        float y = 0.f;
        if (tid < 64) {
            for (int k = 0; k < 64; k++) y += M2sh[k * 64 + tid] * v0[k];
        }
        float yy = y * y;
        #pragma unroll
        for (int off = 32; off; off >>= 1) yy += __shfl_down(yy, off, 64);
        float nrm = __shfl(yy, 0, 64);
        if (tid < 64) v1[tid] = y * rsqrtf(fmaxf(nrm, 1e-30f));
        __syncthreads();
        if (tid < 64) v0[tid] = v1[tid];
        __syncthreads();
    }
    {   /* lambda = v^T M v  (v normalized) */
        float a = 0.f;
        if (tid < 64) {
            for (int k = 0; k < 64; k++) a += Msh[k * 64 + tid] * v0[k];
            a *= v0[tid];
        }
        #pragma unroll
        for (int off = 32; off; off >>= 1) a += __shfl_down(a, off, 64);
        if (tid == 0) lamsh = a;
    }
    __syncthreads();
    const float sigma = sqrtf(fmaxf(lamsh, 1e-30f));
    const float tau = tanhf(temperature[0]);
    if (tid < 64) {
        float gp = bn_gamma[tid] * rsqrtf(bn_var[tid] + 1e-5f);
        ws[OFF_B2 + tid] = tau * (bn_beta[tid] - gp * bn_mean[tid]);
    }
    {
        short* p2b = (short*)(ws + OFF_P2BF);
        for (int q = tid; q < 4096; q += 256) {
            int o = q >> 6;
            float gp = bn_gamma[o] * rsqrtf(bn_var[o] + 1e-5f);
            float v = tau * gp * proj_w[q] / sigma;   /* q = o*64 + c */
            ws[OFF_P2 + q] = v;
            p2b[q] = (short)f2bf(v);
        }
    }
}

/* ------- K3: tile once: fused, S sums, MFMA projection, out = x + P2*fused ------- */
__global__ __launch_bounds__(256) void k3_main(
    const float* __restrict__ x, const float* __restrict__ diff_w,
    const float* __restrict__ unc_w1, const float* __restrict__ unc_b1,
    const float* __restrict__ unc_w2, const float* __restrict__ unc_b2,
    const float* __restrict__ ws, float* __restrict__ out) {
    __shared__ short dls[256 * 64];   /* [tn][c], XOR-swizzled, bf16 */
    const int tile = blockIdx.x;
    const int b = tile / NBLK_PER_B;
    const int n0 = (tile % NBLK_PER_B) * NTILE;
    const int tid = threadIdx.x;
    const int nloc = tid & 31;

    /* ---- phase 1: per (c,n): GP blend, diff conv + BN + gelu -> d into LDS ---- */
    {
        const int n = n0 + nloc;
        float mk[TT];
        #pragma unroll
        for (int t = 0; t < TT; t++) mk[t] = ws[OFF_MASK + t];
        #pragma unroll
        for (int p = 0; p < 8; p++) {
            const int c = (tid >> 5) + (p << 3);
            float xr[TT];
            #pragma unroll
            for (int t = 0; t < TT; t++)
                xr[t] = x[(size_t)((b * TT + t) * C64 + c) * HW + n];
            const float cw = ws[OFF_COVW + b * C64 + c];
            const float* kr = ws + OFF_K + c * (TT * TT);
            float f0[TT];
            #pragma unroll
            for (int s = 0; s < TT; s++) {
                float a = 0.f;
                #pragma unroll
                for (int t = 0; t < TT; t++) a += kr[s * TT + t] * xr[t];
                f0[s] = a * cw + xr[s] * mk[s] * (1.f - cw);
            }
            const float w0 = diff_w[c * 3 + 0], w1 = diff_w[c * 3 + 1], w2 = diff_w[c * 3 + 2];
            const float ac = ws[OFF_AC + c], bc = ws[OFF_BC + c];
            #pragma unroll
            for (int t = 0; t < TT; t++) {
                float pre = w1 * f0[t];
                if (t > 0)      pre += w0 * f0[t - 1];
                if (t < TT - 1) pre += w2 * f0[t + 1];
                dls[swz(t * 32 + nloc, c)] = (short)f2bf(gelu_f(ac * pre + bc));
            }
        }
    }
    __syncthreads();

    /* ---- phase 2: per row tn=tid: unc MLP -> alpha,beta; rescale row; S sums ---- */
    {
        const int t = tid >> 5;
        float dcol[C64];
        #pragma unroll
        for (int j = 0; j < 8; j++) {
            short8 v = *(const short8*)(dls + swz(tid, j * 8));
            #pragma unroll
            for (int i = 0; i < 8; i++) dcol[j * 8 + i] = bf2f((unsigned short)v[i]);
        }
        float u1[16];
        #pragma unroll
        for (int o = 0; o < 16; o++) {
            float a = unc_b1[o];
            const float* wr = unc_w1 + o * C64;
            #pragma unroll
            for (int c = 0; c < C64; c++) a += wr[c] * dcol[c];
            u1[o] = gelu_f(a);
        }
        float mu = unc_b2[0], va = unc_b2[1];
        #pragma unroll
        for (int o = 0; o < 16; o++) {
            mu += unc_w2[o] * u1[o];
            va += unc_w2[16 + o] * u1[o];
        }
        const float vp = va + 1e-6f;
        const float inv = 1.f / (1.f + vp);
        const float alpha = vp * inv;
        const float beta = mu * inv;

        #pragma unroll
        for (int j = 0; j < 8; j++) {
            short8 wv;
            #pragma unroll
            for (int i = 0; i < 8; i++) {
                float f = alpha * dcol[j * 8 + i] + beta;
                wv[i] = (short)f2bf(f);
                /* S[b][c][t] partial: reduce over the 32 lanes sharing t */
                float v = f;
                v += __shfl_xor(v, 1);
                v += __shfl_xor(v, 2);
                v += __shfl_xor(v, 4);
                v += __shfl_xor(v, 8);
                v += __shfl_xor(v, 16);
                if ((tid & 31) == 0)
                    atomicAdd((float*)ws + OFF_S + (b * C64 + (j * 8 + i)) * TT + t, v);
            }
            *(short8*)(dls + swz(tid, j * 8)) = wv;
        }
    }
    __syncthreads();

    /* ---- phase 4: MFMA projection D[o][tn] = P2bf[o][c] * fused[c][tn] ---- */
    {
        const int w = tid >> 6;          /* wave id: cols [w*64, w*64+64) */
        const int l = tid & 63;
        const int l15 = l & 15;
        const int lg = (l >> 4) & 3;
        const short* P2B = (const short*)(ws + OFF_P2BF);
        f32x4 acc[4][4] = {};
        #pragma unroll
        for (int kh = 0; kh < 2; ++kh) {
            const int cb = kh * 32 + lg * 8;
            short8 bfr[4];
            #pragma unroll
            for (int nt = 0; nt < 4; ++nt) {
                const int tn = w * 64 + nt * 16 + l15;
                bfr[nt] = *(const short8*)(dls + swz(tn, cb));
            }
            #pragma unroll
            for (int mt = 0; mt < 4; ++mt) {
                const int o = mt * 16 + l15;
                short8 afr = *(const short8*)(P2B + o * 64 + cb);
                #pragma unroll
                for (int nt = 0; nt < 4; ++nt)
                    acc[mt][nt] = __builtin_amdgcn_mfma_f32_16x16x32_bf16(
                        afr, bfr[nt], acc[mt][nt], 0, 0, 0);
            }
        }
        /* epilogue: out = x + D  (bias3 added by k5_bias) */
        #pragma unroll
        for (int nt = 0; nt < 4; ++nt) {
            const int t = 2 * w + (nt >> 1);
            const int nl = (nt & 1) * 16 + l15;
            #pragma unroll
            for (int mt = 0; mt < 4; ++mt) {
                #pragma unroll
                for (int j = 0; j < 4; ++j) {
                    const int o = mt * 16 + lg * 4 + j;
                    const size_t idx = (size_t)((b * TT + t) * C64 + o) * HW + n0 + nl;
                    out[idx] = x[idx] + acc[mt][nt][j];
                }
            }
        }
    }
}

/* ---------------- K4: bias3[b][o][t] = B2[o] + sum_c P2[o][c]*pm[b][c][t] ---------------- */
__global__ __launch_bounds__(64) void k4_bias(
    const float* __restrict__ pool_w, const float* __restrict__ pool_b,
    float* __restrict__ ws) {
    const int b = blockIdx.x >> 3, t = blockIdx.x & 7;
    const int o = threadIdx.x;
    __shared__ float pm[C64];
    float a = 0.f;
    for (int k = 0; k < 3; k++) {
        int tt = t + k - 1;
        if (tt < 0 || tt >= TT) continue;
        const float* Sp = ws + OFF_S + b * C64 * TT + tt;
        for (int cp = 0; cp < C64; cp++)
            a += pool_w[(o * C64 + cp) * 3 + k] * Sp[cp * TT];
    }
    pm[o] = pool_b[o] + a * (1.0f / (float)HW);
    __syncthreads();
    float bb = ws[OFF_B2 + o];
    const float* pr = ws + OFF_P2 + o * C64;
    for (int c = 0; c < C64; c++) bb += pr[c] * pm[c];
    ws[OFF_BIAS3 + (b * C64 + o) * TT + t] = bb;
}

/* ---------------- K5: out[bt,o,:] += bias3[b][o][t]  (broadcast RMW) ---------------- */
__global__ __launch_bounds__(256) void k5_bias(
    const float* __restrict__ ws, float* __restrict__ out) {
    const int plane = blockIdx.x;               /* bt*64 + o */
    const int o = plane & 63;
    const int bt = plane >> 6;
    const int b = bt >> 3, t = bt & 7;
    const float bias = ws[OFF_BIAS3 + (b * C64 + o) * TT + t];
    float4* p = reinterpret_cast<float4*>(out + (size_t)plane * HW);
    #pragma unroll
    for (int i = 0; i < 9; i++) {
        const int idx = threadIdx.x + i * 256;
        float4 v = p[idx];
        v.x += bias; v.y += bias; v.z += bias; v.w += bias;
        p[idx] = v;
    }
}

extern "C" void kernel_launch(void* const* d_in, const int* in_sizes, int n_in,
                              void* d_out, int out_size, void* d_ws, size_t ws_size,
                              hipStream_t stream) {
    const float* x           = (const float*)d_in[0];
    const float* tk          = (const float*)d_in[2];
    const float* kw          = (const float*)d_in[3];
    const float* lsc         = (const float*)d_in[4];
    const float* tb          = (const float*)d_in[5];
    const float* sc_w1       = (const float*)d_in[6];
    const float* sc_b1       = (const float*)d_in[7];
    const float* sc_w2       = (const float*)d_in[8];
    const float* sc_b2       = (const float*)d_in[9];
    const float* diff_w      = (const float*)d_in[10];
    const float* diff_gamma  = (const float*)d_in[11];
    const float* diff_beta   = (const float*)d_in[12];
    const float* diff_mean   = (const float*)d_in[13];
    const float* diff_var    = (const float*)d_in[14];
    const float* unc_w1      = (const float*)d_in[15];
    const float* unc_b1      = (const float*)d_in[16];
    const float* unc_w2      = (const float*)d_in[17];
    const float* unc_b2      = (const float*)d_in[18];
    const float* pool_w      = (const float*)d_in[19];
    const float* pool_b      = (const float*)d_in[20];
    const float* proj_w      = (const float*)d_in[21];
    const float* bn_gamma    = (const float*)d_in[22];
    const float* bn_beta     = (const float*)d_in[23];
    const float* bn_mean     = (const float*)d_in[24];
    const float* bn_var      = (const float*)d_in[25];
    const float* temperature = (const float*)d_in[26];
    float* ws = (float*)d_ws;
    float* out = (float*)d_out;

    hipMemsetAsync(ws, 0, ZERO_N * sizeof(float), stream);
    k1_gsum<<<dim3(BB * TT * C64), dim3(256), 0, stream>>>(x, ws);
    k2_prep<<<dim3(1), dim3(256), 0, stream>>>(tk, kw, lsc, tb, sc_w1, sc_b1,
                                               sc_w2, sc_b2, diff_gamma, diff_beta,
                                               diff_mean, diff_var, proj_w, bn_gamma,
                                               bn_beta, bn_mean, bn_var, temperature, ws);
    k3_main<<<dim3(BB * NBLK_PER_B), dim3(256), 0, stream>>>(x, diff_w, unc_w1, unc_b1,
                                                             unc_w2, unc_b2, ws, out);
    k4_bias<<<dim3(BB * TT), dim3(64), 0, stream>>>(pool_w, pool_b, ws);
    k5_bias<<<dim3(BB * TT * C64), dim3(256), 0, stream>>>(ws, out);
}